// Round 3
// baseline (107.421 us; speedup 1.0000x reference)
//
#include <hip/hip_runtime.h>

typedef int i32x4 __attribute__((ext_vector_type(4)));

#define QMAXF 127.0f

// ---------------------------------------------------------------------------
// Weight quantization: one block per output row (cout).
// ws[row] = max(|w[row,:]*s|)/127 ; qw[row,k] = rint(w[row,k]*s / ws[row])
// ---------------------------------------------------------------------------
__global__ __launch_bounds__(256) void quant_w_kernel(
    const float* __restrict__ w, const float* __restrict__ act_scale,
    signed char* __restrict__ qw, float* __restrict__ wscale)
{
    const int row = blockIdx.x;
    const int t   = threadIdx.x;
    const float s = act_scale[0];

    float4 v = *reinterpret_cast<const float4*>(w + (size_t)row * 1024 + t * 4);
    float a0 = v.x * s, a1 = v.y * s, a2 = v.z * s, a3 = v.w * s;
    float m = fmaxf(fmaxf(fabsf(a0), fabsf(a1)), fmaxf(fabsf(a2), fabsf(a3)));

    // wave-64 butterfly max
    #pragma unroll
    for (int i = 1; i < 64; i <<= 1)
        m = fmaxf(m, __shfl_xor(m, i));

    __shared__ float wmax[4];
    if ((t & 63) == 0) wmax[t >> 6] = m;
    __syncthreads();
    m = fmaxf(fmaxf(wmax[0], wmax[1]), fmaxf(wmax[2], wmax[3]));

    const float wsc = m / QMAXF;

    int q0 = (int)rintf(a0 / wsc);
    int q1 = (int)rintf(a1 / wsc);
    int q2 = (int)rintf(a2 / wsc);
    int q3 = (int)rintf(a3 / wsc);
    int packed = (q0 & 255) | ((q1 & 255) << 8) | ((q2 & 255) << 16) | ((q3 & 255) << 24);
    reinterpret_cast<int*>(qw)[row * 256 + t] = packed;

    if (t == 0) wscale[row] = wsc;
}

// ---------------------------------------------------------------------------
// Activation quantization: xq = rint(clip(x/s, -127, 127)), 4 elems/thread.
// ---------------------------------------------------------------------------
__global__ __launch_bounds__(256) void quant_x_kernel(
    const float* __restrict__ x, const float* __restrict__ act_scale,
    signed char* __restrict__ xq)
{
    const float s = act_scale[0];
    const size_t i = ((size_t)blockIdx.x * 256 + threadIdx.x) * 4;
    float4 v = *reinterpret_cast<const float4*>(x + i);
    int q0 = (int)rintf(fminf(fmaxf(v.x / s, -QMAXF), QMAXF));
    int q1 = (int)rintf(fminf(fmaxf(v.y / s, -QMAXF), QMAXF));
    int q2 = (int)rintf(fminf(fmaxf(v.z / s, -QMAXF), QMAXF));
    int q3 = (int)rintf(fminf(fmaxf(v.w / s, -QMAXF), QMAXF));
    int packed = (q0 & 255) | ((q1 & 255) << 8) | ((q2 & 255) << 16) | ((q3 & 255) << 24);
    reinterpret_cast<int*>(xq)[i >> 2] = packed;
}

// ---------------------------------------------------------------------------
// int8 GEMM: C[m,n] = sum_k xq[m,k]*qw[n,k];  y = (float)C * wscale[n] + bias[n]
// 128x128 tile, 4 waves (2x2), BK=64, mfma_i32_16x16x64_i8.
// global_load_lds width-16 staging; XOR slot swizzle (slot ^ (row&3)) applied
// on the GLOBAL source (LDS dest must stay linear) and re-applied on ds_read.
// ---------------------------------------------------------------------------
#define BM 128
#define BN 128
#define BK 64

__global__ __launch_bounds__(256) void gemm_i8_kernel(
    const signed char* __restrict__ xq, const signed char* __restrict__ qw,
    const float* __restrict__ wscale, const float* __restrict__ bias,
    float* __restrict__ out, int M, int N, int K)
{
    __shared__ signed char As[BM * BK];
    __shared__ signed char Bs[BN * BK];

    const int t    = threadIdx.x;
    const int lane = t & 63;
    const int wv   = t >> 6;       // wave 0..3
    const int wm   = wv >> 1;      // 0..1  (M half)
    const int wn   = wv & 1;       // 0..1  (N half)
    const int lrow = lane & 15;
    const int ks   = lane >> 4;    // 0..3 (K slot, 16 bytes each)

    const int m0 = blockIdx.y * BM;
    const int n0 = blockIdx.x * BN;

    i32x4 acc[4][4] = {};

    for (int kt = 0; kt < K; kt += BK) {
        // ---- stage A (128x64 int8 = 8KB): 2 issues of 16B per thread ----
        #pragma unroll
        for (int j = 0; j < 2; j++) {
            int idx  = j * 256 + t;          // 0..511
            int row  = idx >> 2;             // 0..127
            int slot = idx & 3;              // 0..3
            int gs   = slot ^ (row & 3);     // pre-swizzled global source slot
            const signed char* src = xq + (size_t)(m0 + row) * K + kt + gs * 16;
            __builtin_amdgcn_global_load_lds(
                (const __attribute__((address_space(1))) void*)src,
                (__attribute__((address_space(3))) void*)(As + idx * 16), 16, 0, 0);
        }
        // ---- stage B (128x64 int8 = 8KB) ----
        #pragma unroll
        for (int j = 0; j < 2; j++) {
            int idx  = j * 256 + t;
            int row  = idx >> 2;
            int slot = idx & 3;
            int gs   = slot ^ (row & 3);
            const signed char* src = qw + (size_t)(n0 + row) * K + kt + gs * 16;
            __builtin_amdgcn_global_load_lds(
                (const __attribute__((address_space(1))) void*)src,
                (__attribute__((address_space(3))) void*)(Bs + idx * 16), 16, 0, 0);
        }
        __syncthreads();   // compiler emits vmcnt(0) drain + barrier

        i32x4 af[4], bf[4];
        #pragma unroll
        for (int mf = 0; mf < 4; mf++) {
            int row = wm * 64 + mf * 16 + lrow;
            af[mf] = *reinterpret_cast<const i32x4*>(
                &As[row * BK + ((ks ^ (row & 3)) << 4)]);
        }
        #pragma unroll
        for (int nf = 0; nf < 4; nf++) {
            int row = wn * 64 + nf * 16 + lrow;
            bf[nf] = *reinterpret_cast<const i32x4*>(
                &Bs[row * BK + ((ks ^ (row & 3)) << 4)]);
        }

        #pragma unroll
        for (int mf = 0; mf < 4; mf++)
            #pragma unroll
            for (int nf = 0; nf < 4; nf++)
                acc[mf][nf] = __builtin_amdgcn_mfma_i32_16x16x64_i8(
                    af[mf], bf[nf], acc[mf][nf], 0, 0, 0);

        __syncthreads();
    }

    // ---- epilogue: dequant + bias ----
    float wsv[4], bv[4];
    int   gnc[4];
    #pragma unroll
    for (int nf = 0; nf < 4; nf++) {
        int gn = n0 + wn * 64 + nf * 16 + lrow;
        gnc[nf] = gn;
        wsv[nf] = wscale[gn];
        bv[nf]  = bias[gn];
    }
    #pragma unroll
    for (int mf = 0; mf < 4; mf++) {
        #pragma unroll
        for (int r = 0; r < 4; r++) {
            int gm = m0 + wm * 64 + mf * 16 + ks * 4 + r;
            float* orow = out + (size_t)gm * N;
            #pragma unroll
            for (int nf = 0; nf < 4; nf++) {
                orow[gnc[nf]] = (float)acc[mf][nf][r] * wsv[nf] + bv[nf];
            }
        }
    }
}

// ---------------------------------------------------------------------------
extern "C" void kernel_launch(void* const* d_in, const int* in_sizes, int n_in,
                              void* d_out, int out_size, void* d_ws, size_t ws_size,
                              hipStream_t stream)
{
    const float* x         = (const float*)d_in[0];
    const float* weight    = (const float*)d_in[1];
    const float* bias      = (const float*)d_in[2];
    const float* act_scale = (const float*)d_in[3];
    float* out             = (float*)d_out;

    const int K = 1024;
    const int N = 1024;
    const int M = in_sizes[0] / K;   // 32768

    // workspace layout: qw (N*K int8) | wscale (N f32, padded) | xq (M*K int8)
    char* wsb = (char*)d_ws;
    signed char* qw   = (signed char*)wsb;
    float*       wsc  = (float*)(wsb + (size_t)N * K);
    signed char* xq   = (signed char*)(wsb + (size_t)N * K + 4096);

    quant_w_kernel<<<N, 256, 0, stream>>>(weight, act_scale, qw, wsc);
    quant_x_kernel<<<(int)(((size_t)M * K) / 1024), 256, 0, stream>>>(x, act_scale, xq);

    dim3 grid(N / BN, M / BM);
    gemm_i8_kernel<<<grid, 256, 0, stream>>>(xq, qw, wsc, bias, out, M, N, K);
}

// Round 4
// 86.349 us; speedup vs baseline: 1.2440x; 1.2440x over previous
//
#include <hip/hip_runtime.h>

typedef int i32x4 __attribute__((ext_vector_type(4)));

#define QMAXF 127.0f

// ---------------------------------------------------------------------------
// Weight quantization (unchanged — ~2 µs, trivial)
// ---------------------------------------------------------------------------
__global__ __launch_bounds__(256) void quant_w_kernel(
    const float* __restrict__ w, const float* __restrict__ act_scale,
    signed char* __restrict__ qw, float* __restrict__ wscale)
{
    const int row = blockIdx.x;
    const int t   = threadIdx.x;
    const float s = act_scale[0];

    float4 v = *reinterpret_cast<const float4*>(w + (size_t)row * 1024 + t * 4);
    float a0 = v.x * s, a1 = v.y * s, a2 = v.z * s, a3 = v.w * s;
    float m = fmaxf(fmaxf(fabsf(a0), fabsf(a1)), fmaxf(fabsf(a2), fabsf(a3)));

    #pragma unroll
    for (int i = 1; i < 64; i <<= 1)
        m = fmaxf(m, __shfl_xor(m, i));

    __shared__ float wmax[4];
    if ((t & 63) == 0) wmax[t >> 6] = m;
    __syncthreads();
    m = fmaxf(fmaxf(wmax[0], wmax[1]), fmaxf(wmax[2], wmax[3]));

    const float wsc = m / QMAXF;

    int q0 = (int)rintf(a0 / wsc);
    int q1 = (int)rintf(a1 / wsc);
    int q2 = (int)rintf(a2 / wsc);
    int q3 = (int)rintf(a3 / wsc);
    int packed = (q0 & 255) | ((q1 & 255) << 8) | ((q2 & 255) << 16) | ((q3 & 255) << 24);
    reinterpret_cast<int*>(qw)[row * 256 + t] = packed;

    if (t == 0) wscale[row] = wsc;
}

// ---------------------------------------------------------------------------
// Activation quantization (unchanged — at BW floor ~23 µs)
// ---------------------------------------------------------------------------
__global__ __launch_bounds__(256) void quant_x_kernel(
    const float* __restrict__ x, const float* __restrict__ act_scale,
    signed char* __restrict__ xq)
{
    const float s = act_scale[0];
    const size_t i = ((size_t)blockIdx.x * 256 + threadIdx.x) * 4;
    float4 v = *reinterpret_cast<const float4*>(x + i);
    int q0 = (int)rintf(fminf(fmaxf(v.x / s, -QMAXF), QMAXF));
    int q1 = (int)rintf(fminf(fmaxf(v.y / s, -QMAXF), QMAXF));
    int q2 = (int)rintf(fminf(fmaxf(v.z / s, -QMAXF), QMAXF));
    int q3 = (int)rintf(fminf(fmaxf(v.w / s, -QMAXF), QMAXF));
    int packed = (q0 & 255) | ((q1 & 255) << 8) | ((q2 & 255) << 16) | ((q3 & 255) << 24);
    reinterpret_cast<int*>(xq)[i >> 2] = packed;
}

// ---------------------------------------------------------------------------
// int8 GEMM — 256x256 tile, 8 waves (2Mx4N), BK=128 int8 (128 B/row, same
// byte geometry as the verified bf16 8-phase template), 8-phase schedule with
// counted vmcnt(4), slot^(row&7) LDS swizzle (pre-swizzled global source,
// linear gload_lds dest), setprio around MFMA clusters, XCD-aware swizzle.
//
// Per K-tile (128 elems): 4 phases, each = one C-quadrant (mh,nh) x K=128 =
// 16 mfma_i32_16x16x64_i8. Stage plan per iteration (tiles T=2i even->buf0,
// T+1 odd->buf1):
//   P1: A0(T+1)  P2: A1(T+1)  P3: B0(T+2)  P4: B1(T+2) +vmcnt(4)
//   P5: A0(T+2)  P6: A1(T+2)  P7: B0(T+3)  P8: B1(T+3) +vmcnt(4)
// vmcnt(4) leaves exactly the 2 newest halves in flight; drains everything
// the next 4 phases read. Prologue: tile0 full + tile1 B halves, vmcnt(4).
// Last iteration: missing stages -> vmcnt(0) at P4.
// ---------------------------------------------------------------------------
#define BM 256
#define BN 256
#define BKB 128
#define NTILES 8   // K / BKB = 1024/128

#define BAR()   __builtin_amdgcn_s_barrier()
#define LGKM0() asm volatile("s_waitcnt lgkmcnt(0)" ::: "memory")

__global__ __launch_bounds__(512, 2) void gemm_i8_kernel(
    const signed char* __restrict__ xq, const signed char* __restrict__ qw,
    const float* __restrict__ wscale, const float* __restrict__ bias,
    float* __restrict__ out, int M)
{
    const int K = 1024, N = 1024;
    __shared__ __align__(16) signed char lds[2 * 2 * 2 * 16384]; // [buf][A/B][half][16KB] = 128 KiB

    const int t    = threadIdx.x;
    const int lane = t & 63;
    const int w    = t >> 6;       // wave 0..7
    const int wr   = w >> 2;       // 0..1 (M half of block)
    const int wc   = w & 3;        // 0..3 (N quarter of block)
    const int lrow = lane & 15;
    const int ks   = lane >> 4;    // 0..3 (16B K-slot)
    const int r8   = lane >> 3;    // 0..7 (staging row in 8-row group)
    const int sl   = lane & 7;     // staging slot

    // XCD-aware bijective swizzle (nwg = (M/256)*4, divisible by 8)
    const int nwg = gridDim.x;
    const int cpx = nwg >> 3;
    const int bid = blockIdx.x;
    const int swz = (bid & 7) * cpx + (bid >> 3);
    const int m0 = (swz >> 2) * BM;   // n-minor: each XCD chunk reuses all of B in L2
    const int n0 = (swz & 3) * BN;

    i32x4 acc[8][4] = {};       // [m-frag][n-frag], 128 VGPRs
    i32x4 Ar[4][2];             // current mh: 4 m-frags x 2 K-steps
    i32x4 Br[2][2][2];          // [nh][nf][kk] — both n-halves live per tile

    // stage one 16KB half-tile: 2 x global_load_lds(16B) per thread.
    // LDS dest linear; global source pre-swizzled: slot_src = sl ^ (row&7).
    auto STAGE = [&](int kt, int ab, int h) {
        const signed char* g = ab ? qw : xq;
        const int grow0 = (ab ? n0 : m0) + h * 128;
        signed char* lb = lds + (((kt & 1) * 2 + ab) * 2 + h) * 16384;
        #pragma unroll
        for (int j = 0; j < 2; ++j) {
            const int row = (j * 8 + w) * 8 + r8;               // row&7 == r8
            const signed char* src =
                g + (size_t)(grow0 + row) * K + kt * BKB + ((sl ^ r8) << 4);
            __builtin_amdgcn_global_load_lds(
                (const __attribute__((address_space(1))) void*)src,
                (__attribute__((address_space(3))) void*)(lb + ((j * 8 + w) * 64 + lane) * 16),
                16, 0, 0);
        }
    };

    auto LDA = [&](int buf, int mh, i32x4 A[4][2]) {
        const signed char* base = lds + ((buf * 2 + 0) * 2 + wr) * 16384;
        #pragma unroll
        for (int mf = 0; mf < 4; ++mf) {
            const int row = mh * 64 + mf * 16 + lrow;
            #pragma unroll
            for (int kk = 0; kk < 2; ++kk) {
                const int slot = (kk * 4 + ks) ^ (lrow & 7);    // row&7 == lrow&7
                A[mf][kk] = *reinterpret_cast<const i32x4*>(base + row * 128 + slot * 16);
            }
        }
    };
    auto LDB = [&](int buf, int nh, i32x4 B[2][2]) {
        const signed char* base = lds + ((buf * 2 + 1) * 2 + (wc >> 1)) * 16384;
        #pragma unroll
        for (int nf = 0; nf < 2; ++nf) {
            const int row = (wc & 1) * 64 + nh * 32 + nf * 16 + lrow;
            #pragma unroll
            for (int kk = 0; kk < 2; ++kk) {
                const int slot = (kk * 4 + ks) ^ (lrow & 7);
                B[nf][kk] = *reinterpret_cast<const i32x4*>(base + row * 128 + slot * 16);
            }
        }
    };
    auto MM = [&](int mh, int nh, i32x4 A[4][2], i32x4 B[2][2]) {
        __builtin_amdgcn_s_setprio(1);
        #pragma unroll
        for (int mf = 0; mf < 4; ++mf)
            #pragma unroll
            for (int nf = 0; nf < 2; ++nf)
                #pragma unroll
                for (int kk = 0; kk < 2; ++kk)
                    acc[mh * 4 + mf][nh * 2 + nf] = __builtin_amdgcn_mfma_i32_16x16x64_i8(
                        A[mf][kk], B[nf][kk], acc[mh * 4 + mf][nh * 2 + nf], 0, 0, 0);
        __builtin_amdgcn_s_setprio(0);
    };

    // ---- prologue: tile0 (all 4 halves) + tile1 B halves; drain tile0 ----
    STAGE(0, 1, 0); STAGE(0, 1, 1); STAGE(0, 0, 0); STAGE(0, 0, 1);
    STAGE(1, 1, 0); STAGE(1, 1, 1);
    asm volatile("s_waitcnt vmcnt(4)" ::: "memory");
    BAR();

    #pragma unroll
    for (int it = 0; it < NTILES / 2; ++it) {
        const int T = 2 * it;
        // -------- P1: Q(0,0) of tile T --------
        LDA(0, 0, Ar); LDB(0, 0, Br[0]);
        STAGE(T + 1, 0, 0);
        BAR(); LGKM0();
        MM(0, 0, Ar, Br[0]);
        BAR();
        // -------- P2: Q(0,1) --------
        LDB(0, 1, Br[1]);
        STAGE(T + 1, 0, 1);
        BAR(); LGKM0();
        MM(0, 1, Ar, Br[1]);
        BAR();
        // -------- P3: Q(1,0) --------
        LDA(0, 1, Ar);
        if (T + 2 < NTILES) STAGE(T + 2, 1, 0);
        BAR(); LGKM0();
        MM(1, 0, Ar, Br[0]);
        BAR();
        // -------- P4: Q(1,1) + vmcnt --------
        if (T + 2 < NTILES) STAGE(T + 2, 1, 1);
        MM(1, 1, Ar, Br[1]);
        if (T + 2 < NTILES) { asm volatile("s_waitcnt vmcnt(4)" ::: "memory"); }
        else                { asm volatile("s_waitcnt vmcnt(0)" ::: "memory"); }
        BAR();
        // -------- P5: Q(0,0) of tile T+1 --------
        LDA(1, 0, Ar); LDB(1, 0, Br[0]);
        if (T + 2 < NTILES) STAGE(T + 2, 0, 0);
        BAR(); LGKM0();
        MM(0, 0, Ar, Br[0]);
        BAR();
        // -------- P6: Q(0,1) --------
        LDB(1, 1, Br[1]);
        if (T + 2 < NTILES) STAGE(T + 2, 0, 1);
        BAR(); LGKM0();
        MM(0, 1, Ar, Br[1]);
        BAR();
        // -------- P7: Q(1,0) --------
        LDA(1, 1, Ar);
        if (T + 3 < NTILES) STAGE(T + 3, 1, 0);
        BAR(); LGKM0();
        MM(1, 0, Ar, Br[0]);
        BAR();
        // -------- P8: Q(1,1) + vmcnt --------
        if (T + 3 < NTILES) STAGE(T + 3, 1, 1);
        MM(1, 1, Ar, Br[1]);
        if (T + 3 < NTILES) { asm volatile("s_waitcnt vmcnt(4)" ::: "memory"); }
        BAR();
    }

    // ---- epilogue: dequant + bias ----
    float wsv[4], bv[4];
    int   gnc[4];
    #pragma unroll
    for (int nf = 0; nf < 4; ++nf) {
        const int gn = n0 + wc * 64 + nf * 16 + lrow;
        gnc[nf] = gn;
        wsv[nf] = wscale[gn];
        bv[nf]  = bias[gn];
    }
    #pragma unroll
    for (int mf = 0; mf < 8; ++mf) {
        #pragma unroll
        for (int r = 0; r < 4; ++r) {
            const int gm = m0 + wr * 128 + mf * 16 + ks * 4 + r;
            float* orow = out + (size_t)gm * N;
            #pragma unroll
            for (int nf = 0; nf < 4; ++nf)
                orow[gnc[nf]] = (float)acc[mf][nf][r] * wsv[nf] + bv[nf];
        }
    }
}

// ---------------------------------------------------------------------------
extern "C" void kernel_launch(void* const* d_in, const int* in_sizes, int n_in,
                              void* d_out, int out_size, void* d_ws, size_t ws_size,
                              hipStream_t stream)
{
    const float* x         = (const float*)d_in[0];
    const float* weight    = (const float*)d_in[1];
    const float* bias      = (const float*)d_in[2];
    const float* act_scale = (const float*)d_in[3];
    float* out             = (float*)d_out;

    const int K = 1024;
    const int N = 1024;
    const int M = in_sizes[0] / K;   // 32768

    // workspace: qw (N*K int8) | wscale (N f32, padded to 4KB) | xq (M*K int8)
    char* wsb = (char*)d_ws;
    signed char* qw  = (signed char*)wsb;
    float*       wsc = (float*)(wsb + (size_t)N * K);
    signed char* xq  = (signed char*)(wsb + (size_t)N * K + 4096);

    quant_w_kernel<<<N, 256, 0, stream>>>(weight, act_scale, qw, wsc);
    quant_x_kernel<<<(int)(((size_t)M * K) / 1024), 256, 0, stream>>>(x, act_scale, xq);

    const int grid = (M / BM) * (N / BN);   // 128*4 = 512, divisible by 8
    gemm_i8_kernel<<<grid, 512, 0, stream>>>(xq, qw, wsc, bias, out, M);
}